// Round 3
// baseline (569.653 us; speedup 1.0000x reference)
//
#include <hip/hip_runtime.h>
#include <hip/hip_bf16.h>
#include <math.h>

// out[i,j,:] = sinusoidal_emb(atan2(|n_i x n_j|, n_i.n_j) * 180/(15pi)) @ W.T + b
// N=1024^2 pairs, HIDDEN=128. Inputs fp32, OUTPUT fp32 (reference dtype; R2's
// 3.39 absmax was the bf16-write-into-fp32-buffer signature). Output
// 1M x 128 fp32 = 512 MiB -> HBM-write-bound (~85us floor at 6.3 TB/s).
// Output row is a smooth 1-D function of the angle alone -> precompute a
// 127-row table of (emb @ W.T + b) over the angle grid, lerp per pair.
// Lerp err ~7e-4 << 4.8e-2 threshold.

#define N_PTS 1024
#define HID   128
#define K_TAB 127                 // 127*128*4 = 65024 B table (fits 64KB static LDS)
#define A_MAX 12.0f               // max a_index = pi * 180/(15*pi) = 12 exactly
#define T_OF_ANGLE 40.1070456591f // (K_TAB-1)/pi = 126/pi
#define NEG_LOG1E4_OVER_128 (-0.0719557841f)

// ---------------- Kernel A: build table T[K_TAB][HID] (fp32, in ws) ----------------
// T[t][k] = b[k] + sum_m sin(a_t*w_m)*W[k][2m] + cos(a_t*w_m)*W[k][2m+1]
__global__ __launch_bounds__(128) void build_table(
        const float* __restrict__ W,
        const float* __restrict__ b,
        float* __restrict__ T) {
    __shared__ float ss[64], sc[64];
    const int t = blockIdx.x;                      // 0..K_TAB-1
    const float a = (float)t * (A_MAX / (float)(K_TAB - 1));
    const int k = threadIdx.x;                     // 0..127
    if (k < 64) {
        float omega = expf((float)(2 * k) * NEG_LOG1E4_OVER_128); // 10000^(-k/64)
        ss[k] = sinf(a * omega);
        sc[k] = cosf(a * omega);
    }
    __syncthreads();
    float acc = b[k];
    const float* wrow = W + k * HID;
#pragma unroll 8
    for (int m = 0; m < 64; ++m) {
        acc += ss[m] * wrow[2 * m] + sc[m] * wrow[2 * m + 1];
    }
    T[t * HID + k] = acc;
}

// ---------------- Kernel B: per-pair angle -> table coordinate t ----------------
__global__ __launch_bounds__(256) void compute_t(
        const float* __restrict__ normals,
        float* __restrict__ tv) {
    const int p = blockIdx.x * 256 + threadIdx.x;
    const int i = p >> 10;        // ref index
    const int j = p & 1023;       // anc index
    float ax = normals[3 * i],     ay = normals[3 * i + 1], az = normals[3 * i + 2];
    float bx = normals[3 * j],     by = normals[3 * j + 1], bz = normals[3 * j + 2];
    float cx = ay * bz - az * by;
    float cy = az * bx - ax * bz;
    float cz = ax * by - ay * bx;
    float sv = sqrtf(cx * cx + cy * cy + cz * cz);
    float cv = ax * bx + ay * by + az * bz;
    float ang = atan2f(sv, cv);   // [0, pi]
    tv[p] = ang * T_OF_ANGLE;     // [0, 126]
}

// ---------------- Kernel C: lerp table rows (fp32), stream out ----------------
__device__ __forceinline__ float4 lerp4(const float* __restrict__ lt,
                                        float t, int lane) {
    int idx = (int)floorf(t);
    idx = idx < 0 ? 0 : (idx > K_TAB - 2 ? K_TAB - 2 : idx);
    float frac = t - (float)idx;
    const float4 v0 = *(const float4*)(lt + idx * HID + lane * 4);
    const float4 v1 = *(const float4*)(lt + idx * HID + HID + lane * 4);
    float4 v;
    v.x = fmaf(frac, v1.x - v0.x, v0.x);
    v.y = fmaf(frac, v1.y - v0.y, v0.y);
    v.z = fmaf(frac, v1.z - v0.z, v0.z);
    v.w = fmaf(frac, v1.w - v0.w, v0.w);
    return v;
}

__global__ __launch_bounds__(256) void lerp_out(
        const float* __restrict__ T,
        const float* __restrict__ tv,
        float* __restrict__ out) {
    __shared__ float lt[K_TAB * HID];   // 65024 B -> 2 blocks/CU
    for (int idx = threadIdx.x; idx < (K_TAB * HID) / 4; idx += 256)
        ((float4*)lt)[idx] = ((const float4*)T)[idx];
    __syncthreads();

    const int lane  = threadIdx.x & 31;                   // 32 lanes per pair, 4 k each
    const int slot  = (blockIdx.x * 256 + threadIdx.x) >> 5;
    const int nslot = (gridDim.x * 256) >> 5;
    const int npair2 = (N_PTS * N_PTS) / 2;               // 2 pairs per iter

    for (int p2 = slot; p2 < npair2; p2 += nslot) {
        const int p = p2 * 2;
        const float2 tt = *(const float2*)(tv + p);       // 8B load per half-wave
        float4 v0 = lerp4(lt, tt.x, lane);
        float4 v1 = lerp4(lt, tt.y, lane);
        // 32 lanes x 16B = 512B contiguous per pair row; two adjacent rows
        *(float4*)(out + (size_t)p * HID + lane * 4) = v0;
        *(float4*)(out + ((size_t)p + 1) * HID + lane * 4) = v1;
    }
}

extern "C" void kernel_launch(void* const* d_in, const int* in_sizes, int n_in,
                              void* d_out, int out_size, void* d_ws, size_t ws_size,
                              hipStream_t stream) {
    // setup_inputs order: points (unused), normals, W, b — fp32 per reference
    const float* normals = (const float*)d_in[1];
    const float* W       = (const float*)d_in[2];
    const float* b       = (const float*)d_in[3];
    float* out           = (float*)d_out;

    // ws layout: [0, 65024) fp32 table; [65536, 65536 + 4MiB) per-pair t coord
    float* T  = (float*)d_ws;
    float* tv = (float*)((char*)d_ws + 65536);

    build_table<<<K_TAB, 128, 0, stream>>>(W, b, T);
    compute_t<<<(N_PTS * N_PTS) / 256, 256, 0, stream>>>(normals, tv);
    // 1024 blocks * 8 pair-slots/block = 8192 slots; 512K pair-pairs / 8192 = 64 iters
    lerp_out<<<1024, 256, 0, stream>>>(T, tv, out);
}